// Round 3
// baseline (897.837 us; speedup 1.0000x reference)
//
#include <hip/hip_runtime.h>

#define NEG_SLOPE 0.2f

// ---------------- CSR build ----------------

__global__ void hist_kernel(const int* __restrict__ ei, int* __restrict__ counts,
                            int E, int Etot) {
  int e = blockIdx.x * blockDim.x + threadIdx.x;
  if (e >= Etot) return;
  int d = (e < E) ? ei[E + e] : (e - E);   // self loop dst = e - E
  atomicAdd(&counts[d], 1);
}

__global__ void mean_kernel(const float* __restrict__ ea, float* __restrict__ acc, int E) {
  int i = blockIdx.x * blockDim.x + threadIdx.x;
  float s = 0.f;
  for (; i < E; i += gridDim.x * blockDim.x) s += ea[i];
#pragma unroll
  for (int off = 1; off < 64; off <<= 1) s += __shfl_xor(s, off, 64);
  if ((threadIdx.x & 63) == 0) atomicAdd(acc, s);
}

// exclusive scan of counts[N] -> rowptr[N], chunk = 4096 per block (256 thr x 16)
__global__ void scan_blocksum(const int* __restrict__ counts, int* __restrict__ bsum, int Nn) {
  int base = blockIdx.x * 4096 + threadIdx.x * 16;
  int s = 0;
#pragma unroll
  for (int i = 0; i < 16; i++) { int idx = base + i; if (idx < Nn) s += counts[idx]; }
#pragma unroll
  for (int off = 1; off < 64; off <<= 1) s += __shfl_xor(s, off, 64);
  __shared__ int ws_[4];
  if ((threadIdx.x & 63) == 0) ws_[threadIdx.x >> 6] = s;
  __syncthreads();
  if (threadIdx.x == 0) bsum[blockIdx.x] = ws_[0] + ws_[1] + ws_[2] + ws_[3];
}

__global__ void scan_offsets(int* bsum, int nb, int* rowptrN,
                             const float* meanacc, float* meanv, int E) {
  if (threadIdx.x == 0 && blockIdx.x == 0) {
    int acc = 0;
    for (int i = 0; i < nb; i++) { int v = bsum[i]; bsum[i] = acc; acc += v; }
    *rowptrN = acc;                       // rowptr[N] = E'
    *meanv = *meanacc / (float)E;         // finalize edge_attr mean
  }
}

__global__ void scan_final(const int* __restrict__ counts, const int* __restrict__ bsum,
                           int* __restrict__ rowptr, int Nn) {
  int base = blockIdx.x * 4096 + threadIdx.x * 16;
  int v[16]; int s = 0;
#pragma unroll
  for (int i = 0; i < 16; i++) { int idx = base + i; v[i] = (idx < Nn) ? counts[idx] : 0; s += v[i]; }
  int lane = threadIdx.x & 63, wv = threadIdx.x >> 6;
  int incl = s;
#pragma unroll
  for (int off = 1; off < 64; off <<= 1) {
    int y = __shfl_up(incl, off, 64);
    if (lane >= off) incl += y;
  }
  __shared__ int wtot[4];
  if (lane == 63) wtot[wv] = incl;
  __syncthreads();
  int run = bsum[blockIdx.x] + incl - s;
  for (int i = 0; i < wv; i++) run += wtot[i];
  for (int i = 0; i < 16; i++) {
    int idx = base + i;
    if (idx < Nn) rowptr[idx] = run;
    run += v[i];
  }
}

__global__ void scatter_kernel(const int* __restrict__ ei, int* __restrict__ cursor,
                               int* __restrict__ perm, int E, int Etot) {
  int e = blockIdx.x * blockDim.x + threadIdx.x;
  if (e >= Etot) return;
  int d = (e < E) ? ei[E + e] : (e - E);
  int pos = atomicAdd(&cursor[d], 1);
  perm[pos] = e;
}

// we_att[h] = sum_c We[h*64+c] * att_e[h*64+c]   (one wave per head, block=256)
__global__ void weatt_kernel(const float* __restrict__ We, const float* __restrict__ atte,
                             float* __restrict__ weatt) {
  int t = threadIdx.x;
  float p = We[t] * atte[t];
#pragma unroll
  for (int off = 1; off < 64; off <<= 1) p += __shfl_xor(p, off, 64);
  if ((t & 63) == 0) weatt[t >> 6] = p;
}

// ---------------- dense GEMM: Y[M,256] = X[M,K] @ W[K,256], fp32 ----------------
// block 256 thr computes 64x64 tile, 4x4 per thread, BK=16

__global__ __launch_bounds__(256) void gemm_f32(const float* __restrict__ X,
                                                const float* __restrict__ W,
                                                float* __restrict__ Y, int M, int K) {
  __shared__ float As[16][65];
  __shared__ float Bs[16][64];
  int bm = blockIdx.x * 64, bn = blockIdx.y * 64;
  int tid = threadIdx.x;
  int tx = tid & 15, ty = tid >> 4;
  float acc[4][4] = {};
  for (int k0 = 0; k0 < K; k0 += 16) {
    // A tile: As[kk][m] = X[(bm+m)*K + k0+kk]; thread: kk = tid&15, m = (tid>>4)+16i
    {
      int kk = tid & 15, m0 = tid >> 4;
#pragma unroll
      for (int i = 0; i < 4; i++) {
        int m = m0 + 16 * i;
        int gr = bm + m;
        As[kk][m] = (gr < M) ? X[(size_t)gr * K + k0 + kk] : 0.f;
      }
    }
    // B tile: Bs[kk][n] = W[(k0+kk)*256 + bn+n]; thread: n = tid&63, kk = (tid>>6)+4i
    {
      int n = tid & 63, kb = tid >> 6;
#pragma unroll
      for (int i = 0; i < 4; i++) {
        int kk = kb + 4 * i;
        Bs[kk][n] = W[(size_t)(k0 + kk) * 256 + bn + n];
      }
    }
    __syncthreads();
#pragma unroll
    for (int kk = 0; kk < 16; kk++) {
      float a[4], b[4];
#pragma unroll
      for (int i = 0; i < 4; i++) a[i] = As[kk][ty * 4 + i];
#pragma unroll
      for (int j = 0; j < 4; j++) b[j] = Bs[kk][tx * 4 + j];
#pragma unroll
      for (int i = 0; i < 4; i++)
#pragma unroll
        for (int j = 0; j < 4; j++) acc[i][j] += a[i] * b[j];
    }
    __syncthreads();
  }
#pragma unroll
  for (int i = 0; i < 4; i++) {
    int gr = bm + ty * 4 + i;
    if (gr < M) {
#pragma unroll
      for (int j = 0; j < 4; j++) Y[(size_t)gr * 256 + bn + tx * 4 + j] = acc[i][j];
    }
  }
}

// ---------------- a_src / a_dst: one wave per node ----------------

__global__ __launch_bounds__(256) void att_dots(const float* __restrict__ H,
                                                const float* __restrict__ atts,
                                                const float* __restrict__ attd,
                                                float* __restrict__ asrc,
                                                float* __restrict__ adst, int Nn) {
  int wid = (blockIdx.x * blockDim.x + threadIdx.x) >> 6;
  int lane = threadIdx.x & 63;
  if (wid >= Nn) return;
  float4 h = *(const float4*)&H[(size_t)wid * 256 + lane * 4];
  float4 s = *(const float4*)&atts[lane * 4];
  float4 d = *(const float4*)&attd[lane * 4];
  float vs = h.x * s.x + h.y * s.y + h.z * s.z + h.w * s.w;
  float vd = h.x * d.x + h.y * d.y + h.z * d.z + h.w * d.w;
#pragma unroll
  for (int off = 1; off < 16; off <<= 1) {
    vs += __shfl_xor(vs, off, 64);
    vd += __shfl_xor(vd, off, 64);
  }
  if ((lane & 15) == 0) {
    int hh = lane >> 4;
    asrc[wid * 4 + hh] = vs;
    adst[wid * 4 + hh] = vd;
  }
}

// ---------------- attention softmax + aggregation: one wave per dst node ----------------

__global__ __launch_bounds__(256) void gat_agg(const float* __restrict__ H,
                                               const float* __restrict__ asrc,
                                               const float* __restrict__ adst,
                                               const int* __restrict__ rowptr,
                                               const int* __restrict__ perm,
                                               const int* __restrict__ ei,
                                               const float* __restrict__ eattr,
                                               const float* __restrict__ weatt,
                                               const float* __restrict__ meanv,
                                               const float* __restrict__ bias,
                                               float* __restrict__ out, int Nn, int E) {
  int wid = (blockIdx.x * blockDim.x + threadIdx.x) >> 6;
  int lane = threadIdx.x & 63;
  if (wid >= Nn) return;
  int beg = rowptr[wid], end = rowptr[wid + 1];
  int hh = lane >> 4;                 // head for this lane's 4 channels
  float wa = weatt[hh];
  float mea = meanv[0];
  float ad = adst[wid * 4 + hh];

  // pass 1: online max + sum of exp over this node's incoming edges (per head)
  float m = -1e30f, ssum = 0.f;
  for (int p = beg; p < end; p++) {
    int e = perm[p];
    int s = (e < E) ? ei[e] : (e - E);
    float ea = (e < E) ? eattr[e] : mea;
    float al = asrc[s * 4 + hh] + ad + ea * wa;
    al = (al > 0.f) ? al : NEG_SLOPE * al;
    float mn = fmaxf(m, al);
    ssum = ssum * expf(m - mn) + expf(al - mn);
    m = mn;
  }
  float inv = 1.f / (ssum + 1e-16f);

  // pass 2: weighted gather-accumulate of h_lin[src]
  float4 acc = {0.f, 0.f, 0.f, 0.f};
  for (int p = beg; p < end; p++) {
    int e = perm[p];
    int s = (e < E) ? ei[e] : (e - E);
    float ea = (e < E) ? eattr[e] : mea;
    float al = asrc[s * 4 + hh] + ad + ea * wa;
    al = (al > 0.f) ? al : NEG_SLOPE * al;
    float w = expf(al - m) * inv;
    float4 hv = *(const float4*)&H[(size_t)s * 256 + lane * 4];
    acc.x += w * hv.x; acc.y += w * hv.y; acc.z += w * hv.z; acc.w += w * hv.w;
  }
  float4 b4 = *(const float4*)&bias[lane * 4];
  acc.x += b4.x; acc.y += b4.y; acc.z += b4.z; acc.w += b4.w;
  *(float4*)&out[(size_t)wid * 256 + lane * 4] = acc;
}

// ---------------- launcher ----------------

extern "C" void kernel_launch(void* const* d_in, const int* in_sizes, int n_in,
                              void* d_out, int out_size, void* d_ws, size_t ws_size,
                              hipStream_t stream) {
  (void)n_in; (void)out_size; (void)ws_size;
  const float* x     = (const float*)d_in[0];
  const int*   ei    = (const int*)d_in[1];
  // d_in[2] = batch (unused)
  const float* eattr = (const float*)d_in[3];
  const float* W1    = (const float*)d_in[4];
  const float* We1   = (const float*)d_in[5];
  const float* atts1 = (const float*)d_in[6];
  const float* attd1 = (const float*)d_in[7];
  const float* atte1 = (const float*)d_in[8];
  const float* b1    = (const float*)d_in[9];
  const float* W2    = (const float*)d_in[10];
  const float* We2   = (const float*)d_in[11];
  const float* atts2 = (const float*)d_in[12];
  const float* attd2 = (const float*)d_in[13];
  const float* atte2 = (const float*)d_in[14];
  const float* b2    = (const float*)d_in[15];
  float* out = (float*)d_out;

  const int Nn   = in_sizes[0] / 128;   // 50000
  const int E    = in_sizes[1] / 2;     // 800000
  const int Etot = E + Nn;              // 850000

  // workspace carve (256B aligned)
  char* p = (char*)d_ws;
  auto alloc = [&](size_t bytes) { void* r = (void*)p; p += (bytes + 255) & ~(size_t)255; return r; };
  int*   rowptr  = (int*)alloc((size_t)(Nn + 1) * 4);
  int*   cursor  = (int*)alloc((size_t)Nn * 4);
  int*   counts  = (int*)alloc((size_t)Nn * 4);
  int*   perm    = (int*)alloc((size_t)Etot * 4);
  int*   bsum    = (int*)alloc(64 * 4);
  float* meanacc = (float*)alloc(4);
  float* meanv   = (float*)alloc(4);
  float* weatt1  = (float*)alloc(16);
  float* weatt2  = (float*)alloc(16);
  float* asrc    = (float*)alloc((size_t)Nn * 4 * 4);
  float* adst    = (float*)alloc((size_t)Nn * 4 * 4);
  float* hlin    = (float*)alloc((size_t)Nn * 256 * 4);

  const int NB = (Nn + 4095) / 4096;

  hipMemsetAsync(counts, 0, (size_t)Nn * 4, stream);
  hipMemsetAsync(meanacc, 0, 4, stream);

  hist_kernel<<<(Etot + 255) / 256, 256, 0, stream>>>(ei, counts, E, Etot);
  mean_kernel<<<512, 256, 0, stream>>>(eattr, meanacc, E);
  scan_blocksum<<<NB, 256, 0, stream>>>(counts, bsum, Nn);
  scan_offsets<<<1, 64, 0, stream>>>(bsum, NB, rowptr + Nn, meanacc, meanv, E);
  scan_final<<<NB, 256, 0, stream>>>(counts, bsum, rowptr, Nn);
  hipMemcpyAsync(cursor, rowptr, (size_t)Nn * 4, hipMemcpyDeviceToDevice, stream);
  scatter_kernel<<<(Etot + 255) / 256, 256, 0, stream>>>(ei, cursor, perm, E, Etot);
  weatt_kernel<<<1, 256, 0, stream>>>(We1, atte1, weatt1);
  weatt_kernel<<<1, 256, 0, stream>>>(We2, atte2, weatt2);

  const int gemmGx = (Nn + 63) / 64;
  const int nodeBlocks = (Nn + 3) / 4;   // 4 waves (nodes) per 256-thr block

  // ---- layer 1 ----  (h1 -> d_out, used as layer-2 input)
  gemm_f32<<<dim3(gemmGx, 4), 256, 0, stream>>>(x, W1, hlin, Nn, 128);
  att_dots<<<nodeBlocks, 256, 0, stream>>>(hlin, atts1, attd1, asrc, adst, Nn);
  gat_agg<<<nodeBlocks, 256, 0, stream>>>(hlin, asrc, adst, rowptr, perm, ei, eattr,
                                          weatt1, meanv, b1, out, Nn, E);
  // ---- layer 2 ----
  gemm_f32<<<dim3(gemmGx, 4), 256, 0, stream>>>(out, W2, hlin, Nn, 256);
  att_dots<<<nodeBlocks, 256, 0, stream>>>(hlin, atts2, attd2, asrc, adst, Nn);
  gat_agg<<<nodeBlocks, 256, 0, stream>>>(hlin, asrc, adst, rowptr, perm, ei, eattr,
                                          weatt2, meanv, b2, out, Nn, E);
}

// Round 4
// 591.810 us; speedup vs baseline: 1.5171x; 1.5171x over previous
//
#include <hip/hip_runtime.h>

#define NEG_SLOPE 0.2f

// ---------------- CSR build ----------------

__global__ void hist_kernel(const int* __restrict__ ei, int* __restrict__ counts,
                            int E, int Etot) {
  int e = blockIdx.x * blockDim.x + threadIdx.x;
  if (e >= Etot) return;
  int d = (e < E) ? ei[E + e] : (e - E);   // self loop dst = e - E
  atomicAdd(&counts[d], 1);
}

__global__ void mean_kernel(const float* __restrict__ ea, float* __restrict__ acc, int E) {
  int i = blockIdx.x * blockDim.x + threadIdx.x;
  float s = 0.f;
  for (; i < E; i += gridDim.x * blockDim.x) s += ea[i];
#pragma unroll
  for (int off = 1; off < 64; off <<= 1) s += __shfl_xor(s, off, 64);
  if ((threadIdx.x & 63) == 0) atomicAdd(acc, s);
}

// exclusive scan of counts[N] -> rowptr[N], chunk = 4096 per block (256 thr x 16)
__global__ void scan_blocksum(const int* __restrict__ counts, int* __restrict__ bsum, int Nn) {
  int base = blockIdx.x * 4096 + threadIdx.x * 16;
  int s = 0;
#pragma unroll
  for (int i = 0; i < 16; i++) { int idx = base + i; if (idx < Nn) s += counts[idx]; }
#pragma unroll
  for (int off = 1; off < 64; off <<= 1) s += __shfl_xor(s, off, 64);
  __shared__ int ws_[4];
  if ((threadIdx.x & 63) == 0) ws_[threadIdx.x >> 6] = s;
  __syncthreads();
  if (threadIdx.x == 0) bsum[blockIdx.x] = ws_[0] + ws_[1] + ws_[2] + ws_[3];
}

__global__ void scan_offsets(int* bsum, int nb, int* rowptrN,
                             const float* meanacc, float* meanv, int E) {
  if (threadIdx.x == 0 && blockIdx.x == 0) {
    int acc = 0;
    for (int i = 0; i < nb; i++) { int v = bsum[i]; bsum[i] = acc; acc += v; }
    *rowptrN = acc;                       // rowptr[N] = E'
    *meanv = *meanacc / (float)E;         // finalize edge_attr mean
  }
}

__global__ void scan_final(const int* __restrict__ counts, const int* __restrict__ bsum,
                           int* __restrict__ rowptr, int Nn) {
  int base = blockIdx.x * 4096 + threadIdx.x * 16;
  int v[16]; int s = 0;
#pragma unroll
  for (int i = 0; i < 16; i++) { int idx = base + i; v[i] = (idx < Nn) ? counts[idx] : 0; s += v[i]; }
  int lane = threadIdx.x & 63, wv = threadIdx.x >> 6;
  int incl = s;
#pragma unroll
  for (int off = 1; off < 64; off <<= 1) {
    int y = __shfl_up(incl, off, 64);
    if (lane >= off) incl += y;
  }
  __shared__ int wtot[4];
  if (lane == 63) wtot[wv] = incl;
  __syncthreads();
  int run = bsum[blockIdx.x] + incl - s;
  for (int i = 0; i < wv; i++) run += wtot[i];
  for (int i = 0; i < 16; i++) {
    int idx = base + i;
    if (idx < Nn) rowptr[idx] = run;
    run += v[i];
  }
}

// scatter resolves all indirection: epack[pos] = {src, edge_attr_value}
__global__ void scatter_kernel(const int* __restrict__ ei, const float* __restrict__ eattr,
                               const float* __restrict__ meanv,
                               int* __restrict__ cursor, int2* __restrict__ epack,
                               int E, int Etot) {
  int e = blockIdx.x * blockDim.x + threadIdx.x;
  if (e >= Etot) return;
  int d, s; float ea;
  if (e < E) { d = ei[E + e]; s = ei[e]; ea = eattr[e]; }
  else       { d = e - E;     s = e - E; ea = meanv[0]; }
  int pos = atomicAdd(&cursor[d], 1);
  epack[pos] = make_int2(s, __float_as_int(ea));
}

// we_att[h] = sum_c We[h*64+c] * att_e[h*64+c]   (one wave per head, block=256)
__global__ void weatt_kernel(const float* __restrict__ We, const float* __restrict__ atte,
                             float* __restrict__ weatt) {
  int t = threadIdx.x;
  float p = We[t] * atte[t];
#pragma unroll
  for (int off = 1; off < 64; off <<= 1) p += __shfl_xor(p, off, 64);
  if ((t & 63) == 0) weatt[t >> 6] = p;
}

// ---------------- dense GEMM: Y[M,256] = X[M,K] @ W[K,256], fp32 ----------------
// block 256 thr computes 64x64 tile, 4x4 per thread, BK=16

__global__ __launch_bounds__(256) void gemm_f32(const float* __restrict__ X,
                                                const float* __restrict__ W,
                                                float* __restrict__ Y, int M, int K) {
  __shared__ float As[16][65];
  __shared__ float Bs[16][64];
  int bm = blockIdx.x * 64, bn = blockIdx.y * 64;
  int tid = threadIdx.x;
  int tx = tid & 15, ty = tid >> 4;
  float acc[4][4] = {};
  for (int k0 = 0; k0 < K; k0 += 16) {
    {
      int kk = tid & 15, m0 = tid >> 4;
#pragma unroll
      for (int i = 0; i < 4; i++) {
        int m = m0 + 16 * i;
        int gr = bm + m;
        As[kk][m] = (gr < M) ? X[(size_t)gr * K + k0 + kk] : 0.f;
      }
    }
    {
      int n = tid & 63, kb = tid >> 6;
#pragma unroll
      for (int i = 0; i < 4; i++) {
        int kk = kb + 4 * i;
        Bs[kk][n] = W[(size_t)(k0 + kk) * 256 + bn + n];
      }
    }
    __syncthreads();
#pragma unroll
    for (int kk = 0; kk < 16; kk++) {
      float a[4], b[4];
#pragma unroll
      for (int i = 0; i < 4; i++) a[i] = As[kk][ty * 4 + i];
#pragma unroll
      for (int j = 0; j < 4; j++) b[j] = Bs[kk][tx * 4 + j];
#pragma unroll
      for (int i = 0; i < 4; i++)
#pragma unroll
        for (int j = 0; j < 4; j++) acc[i][j] += a[i] * b[j];
    }
    __syncthreads();
  }
#pragma unroll
  for (int i = 0; i < 4; i++) {
    int gr = bm + ty * 4 + i;
    if (gr < M) {
#pragma unroll
      for (int j = 0; j < 4; j++) Y[(size_t)gr * 256 + bn + tx * 4 + j] = acc[i][j];
    }
  }
}

// ---------------- a_src / a_dst: one wave per node ----------------

__global__ __launch_bounds__(256) void att_dots(const float* __restrict__ H,
                                                const float* __restrict__ atts,
                                                const float* __restrict__ attd,
                                                float* __restrict__ asrc,
                                                float* __restrict__ adst, int Nn) {
  int wid = (blockIdx.x * blockDim.x + threadIdx.x) >> 6;
  int lane = threadIdx.x & 63;
  if (wid >= Nn) return;
  float4 h = *(const float4*)&H[(size_t)wid * 256 + lane * 4];
  float4 s = *(const float4*)&atts[lane * 4];
  float4 d = *(const float4*)&attd[lane * 4];
  float vs = h.x * s.x + h.y * s.y + h.z * s.z + h.w * s.w;
  float vd = h.x * d.x + h.y * d.y + h.z * d.z + h.w * d.w;
#pragma unroll
  for (int off = 1; off < 16; off <<= 1) {
    vs += __shfl_xor(vs, off, 64);
    vd += __shfl_xor(vd, off, 64);
  }
  if ((lane & 15) == 0) {
    int hh = lane >> 4;
    asrc[wid * 4 + hh] = vs;
    adst[wid * 4 + hh] = vd;
  }
}

// ---------------- fused single-pass softmax + aggregation: one wave per dst ----------------
// flash-style online softmax with accumulator rescale; 2 interleaved states for ILP/MLP

__global__ __launch_bounds__(256) void gat_agg(const float* __restrict__ H,
                                               const float* __restrict__ asrc,
                                               const float* __restrict__ adst,
                                               const int* __restrict__ rowptr,
                                               const int2* __restrict__ epack,
                                               const float* __restrict__ weatt,
                                               const float* __restrict__ bias,
                                               float* __restrict__ out, int Nn) {
  int wid = (blockIdx.x * blockDim.x + threadIdx.x) >> 6;
  int lane = threadIdx.x & 63;
  if (wid >= Nn) return;
  int beg = rowptr[wid], end = rowptr[wid + 1];
  int hh = lane >> 4;                 // head for this lane's 4 channels
  float wa = weatt[hh];
  float ad = adst[wid * 4 + hh];
  unsigned co = (unsigned)lane * 4u;

  float m0 = -1e30f, s0 = 0.f, m1 = -1e30f, s1 = 0.f;
  float4 a0 = {0.f, 0.f, 0.f, 0.f}, a1 = {0.f, 0.f, 0.f, 0.f};
  int p = beg;
  for (; p + 1 < end; p += 2) {
    int2 e0 = epack[p], e1 = epack[p + 1];
    float al0 = fmaf(__int_as_float(e0.y), wa, asrc[e0.x * 4 + hh] + ad);
    float al1 = fmaf(__int_as_float(e1.y), wa, asrc[e1.x * 4 + hh] + ad);
    al0 = al0 > 0.f ? al0 : al0 * NEG_SLOPE;
    al1 = al1 > 0.f ? al1 : al1 * NEG_SLOPE;
    float4 h0 = *(const float4*)&H[(size_t)((unsigned)e0.x * 256u + co)];
    float4 h1 = *(const float4*)&H[(size_t)((unsigned)e1.x * 256u + co)];
    float mn0 = fmaxf(m0, al0);
    float c0 = __expf(m0 - mn0);
    float w0 = __expf(al0 - mn0);
    m0 = mn0;
    s0 = fmaf(s0, c0, w0);
    a0.x = fmaf(a0.x, c0, w0 * h0.x);
    a0.y = fmaf(a0.y, c0, w0 * h0.y);
    a0.z = fmaf(a0.z, c0, w0 * h0.z);
    a0.w = fmaf(a0.w, c0, w0 * h0.w);
    float mn1 = fmaxf(m1, al1);
    float c1 = __expf(m1 - mn1);
    float w1 = __expf(al1 - mn1);
    m1 = mn1;
    s1 = fmaf(s1, c1, w1);
    a1.x = fmaf(a1.x, c1, w1 * h1.x);
    a1.y = fmaf(a1.y, c1, w1 * h1.y);
    a1.z = fmaf(a1.z, c1, w1 * h1.z);
    a1.w = fmaf(a1.w, c1, w1 * h1.w);
  }
  if (p < end) {                      // odd tail -> state 0
    int2 e0 = epack[p];
    float al0 = fmaf(__int_as_float(e0.y), wa, asrc[e0.x * 4 + hh] + ad);
    al0 = al0 > 0.f ? al0 : al0 * NEG_SLOPE;
    float4 h0 = *(const float4*)&H[(size_t)((unsigned)e0.x * 256u + co)];
    float mn0 = fmaxf(m0, al0);
    float c0 = __expf(m0 - mn0);
    float w0 = __expf(al0 - mn0);
    m0 = mn0;
    s0 = fmaf(s0, c0, w0);
    a0.x = fmaf(a0.x, c0, w0 * h0.x);
    a0.y = fmaf(a0.y, c0, w0 * h0.y);
    a0.z = fmaf(a0.z, c0, w0 * h0.z);
    a0.w = fmaf(a0.w, c0, w0 * h0.w);
  }
  // merge the two states
  float mm = fmaxf(m0, m1);
  float c0 = __expf(m0 - mm), c1 = __expf(m1 - mm);
  float ssum = fmaf(s0, c0, s1 * c1);
  float inv = 1.f / (ssum + 1e-16f);
  float4 b4 = *(const float4*)&bias[co];
  float4 r;
  r.x = fmaf(fmaf(a0.x, c0, a1.x * c1), inv, b4.x);
  r.y = fmaf(fmaf(a0.y, c0, a1.y * c1), inv, b4.y);
  r.z = fmaf(fmaf(a0.z, c0, a1.z * c1), inv, b4.z);
  r.w = fmaf(fmaf(a0.w, c0, a1.w * c1), inv, b4.w);
  *(float4*)&out[(size_t)wid * 256 + co] = r;
}

// ---------------- launcher ----------------

extern "C" void kernel_launch(void* const* d_in, const int* in_sizes, int n_in,
                              void* d_out, int out_size, void* d_ws, size_t ws_size,
                              hipStream_t stream) {
  (void)n_in; (void)out_size; (void)ws_size;
  const float* x     = (const float*)d_in[0];
  const int*   ei    = (const int*)d_in[1];
  // d_in[2] = batch (unused)
  const float* eattr = (const float*)d_in[3];
  const float* W1    = (const float*)d_in[4];
  const float* We1   = (const float*)d_in[5];
  const float* atts1 = (const float*)d_in[6];
  const float* attd1 = (const float*)d_in[7];
  const float* atte1 = (const float*)d_in[8];
  const float* b1    = (const float*)d_in[9];
  const float* W2    = (const float*)d_in[10];
  const float* We2   = (const float*)d_in[11];
  const float* atts2 = (const float*)d_in[12];
  const float* attd2 = (const float*)d_in[13];
  const float* atte2 = (const float*)d_in[14];
  const float* b2    = (const float*)d_in[15];
  float* out = (float*)d_out;

  const int Nn   = in_sizes[0] / 128;   // 50000
  const int E    = in_sizes[1] / 2;     // 800000
  const int Etot = E + Nn;              // 850000

  // workspace carve (256B aligned)
  char* p = (char*)d_ws;
  auto alloc = [&](size_t bytes) { void* r = (void*)p; p += (bytes + 255) & ~(size_t)255; return r; };
  int*   rowptr  = (int*)alloc((size_t)(Nn + 1) * 4);
  int*   cursor  = (int*)alloc((size_t)Nn * 4);
  int*   counts  = (int*)alloc((size_t)Nn * 4);
  int2*  epack   = (int2*)alloc((size_t)Etot * 8);
  int*   bsum    = (int*)alloc(64 * 4);
  float* meanacc = (float*)alloc(4);
  float* meanv   = (float*)alloc(4);
  float* weatt1  = (float*)alloc(16);
  float* weatt2  = (float*)alloc(16);
  float* asrc    = (float*)alloc((size_t)Nn * 4 * 4);
  float* adst    = (float*)alloc((size_t)Nn * 4 * 4);
  float* hlin    = (float*)alloc((size_t)Nn * 256 * 4);

  const int NB = (Nn + 4095) / 4096;

  hipMemsetAsync(counts, 0, (size_t)Nn * 4, stream);
  hipMemsetAsync(meanacc, 0, 4, stream);

  hist_kernel<<<(Etot + 255) / 256, 256, 0, stream>>>(ei, counts, E, Etot);
  mean_kernel<<<512, 256, 0, stream>>>(eattr, meanacc, E);
  scan_blocksum<<<NB, 256, 0, stream>>>(counts, bsum, Nn);
  scan_offsets<<<1, 64, 0, stream>>>(bsum, NB, rowptr + Nn, meanacc, meanv, E);
  scan_final<<<NB, 256, 0, stream>>>(counts, bsum, rowptr, Nn);
  hipMemcpyAsync(cursor, rowptr, (size_t)Nn * 4, hipMemcpyDeviceToDevice, stream);
  scatter_kernel<<<(Etot + 255) / 256, 256, 0, stream>>>(ei, eattr, meanv, cursor, epack, E, Etot);
  weatt_kernel<<<1, 256, 0, stream>>>(We1, atte1, weatt1);
  weatt_kernel<<<1, 256, 0, stream>>>(We2, atte2, weatt2);

  const int gemmGx = (Nn + 63) / 64;
  const int nodeBlocks = (Nn + 3) / 4;   // 4 waves (nodes) per 256-thr block

  // ---- layer 1 ----  (h1 -> d_out, used as layer-2 input)
  gemm_f32<<<dim3(gemmGx, 4), 256, 0, stream>>>(x, W1, hlin, Nn, 128);
  att_dots<<<nodeBlocks, 256, 0, stream>>>(hlin, atts1, attd1, asrc, adst, Nn);
  gat_agg<<<nodeBlocks, 256, 0, stream>>>(hlin, asrc, adst, rowptr, epack,
                                          weatt1, b1, out, Nn);
  // ---- layer 2 ----
  gemm_f32<<<dim3(gemmGx, 4), 256, 0, stream>>>(out, W2, hlin, Nn, 256);
  att_dots<<<nodeBlocks, 256, 0, stream>>>(hlin, atts2, attd2, asrc, adst, Nn);
  gat_agg<<<nodeBlocks, 256, 0, stream>>>(hlin, asrc, adst, rowptr, epack,
                                          weatt2, b2, out, Nn);
}

// Round 5
// 346.472 us; speedup vs baseline: 2.5914x; 1.7081x over previous
//
#include <hip/hip_runtime.h>

#define NEG_SLOPE 0.2f

typedef __attribute__((ext_vector_type(8))) short bf16x8;
typedef __attribute__((ext_vector_type(4))) float f32x4;

__device__ inline unsigned short f2bf(float x) {
  unsigned int u = __float_as_uint(x);
  u += 0x7fffu + ((u >> 16) & 1u);
  return (unsigned short)(u >> 16);
}

// ---------------- CSR build ----------------

__global__ void hist_kernel(const int* __restrict__ ei, int* __restrict__ counts,
                            int E, int Etot) {
  int e = blockIdx.x * blockDim.x + threadIdx.x;
  if (e >= Etot) return;
  int d = (e < E) ? ei[E + e] : (e - E);   // self loop dst = e - E
  atomicAdd(&counts[d], 1);
}

__global__ void mean_kernel(const float* __restrict__ ea, float* __restrict__ acc, int E) {
  int i = blockIdx.x * blockDim.x + threadIdx.x;
  float s = 0.f;
  for (; i < E; i += gridDim.x * blockDim.x) s += ea[i];
#pragma unroll
  for (int off = 1; off < 64; off <<= 1) s += __shfl_xor(s, off, 64);
  if ((threadIdx.x & 63) == 0) atomicAdd(acc, s);
}

__global__ void scan_blocksum(const int* __restrict__ counts, int* __restrict__ bsum, int Nn) {
  int base = blockIdx.x * 4096 + threadIdx.x * 16;
  int s = 0;
#pragma unroll
  for (int i = 0; i < 16; i++) { int idx = base + i; if (idx < Nn) s += counts[idx]; }
#pragma unroll
  for (int off = 1; off < 64; off <<= 1) s += __shfl_xor(s, off, 64);
  __shared__ int ws_[4];
  if ((threadIdx.x & 63) == 0) ws_[threadIdx.x >> 6] = s;
  __syncthreads();
  if (threadIdx.x == 0) bsum[blockIdx.x] = ws_[0] + ws_[1] + ws_[2] + ws_[3];
}

__global__ void scan_offsets(int* bsum, int nb, int* rowptrN,
                             const float* meanacc, float* meanv, int E) {
  if (threadIdx.x == 0 && blockIdx.x == 0) {
    int acc = 0;
    for (int i = 0; i < nb; i++) { int v = bsum[i]; bsum[i] = acc; acc += v; }
    *rowptrN = acc;
    *meanv = *meanacc / (float)E;
  }
}

__global__ void scan_final(const int* __restrict__ counts, const int* __restrict__ bsum,
                           int* __restrict__ rowptr, int Nn) {
  int base = blockIdx.x * 4096 + threadIdx.x * 16;
  int v[16]; int s = 0;
#pragma unroll
  for (int i = 0; i < 16; i++) { int idx = base + i; v[i] = (idx < Nn) ? counts[idx] : 0; s += v[i]; }
  int lane = threadIdx.x & 63, wv = threadIdx.x >> 6;
  int incl = s;
#pragma unroll
  for (int off = 1; off < 64; off <<= 1) {
    int y = __shfl_up(incl, off, 64);
    if (lane >= off) incl += y;
  }
  __shared__ int wtot[4];
  if (lane == 63) wtot[wv] = incl;
  __syncthreads();
  int run = bsum[blockIdx.x] + incl - s;
  for (int i = 0; i < wv; i++) run += wtot[i];
  for (int i = 0; i < 16; i++) {
    int idx = base + i;
    if (idx < Nn) rowptr[idx] = run;
    run += v[i];
  }
}

// scatter resolves all indirection: epack[pos] = {src, edge_attr_value}
__global__ void scatter_kernel(const int* __restrict__ ei, const float* __restrict__ eattr,
                               const float* __restrict__ meanv,
                               int* __restrict__ cursor, int2* __restrict__ epack,
                               int E, int Etot) {
  int e = blockIdx.x * blockDim.x + threadIdx.x;
  if (e >= Etot) return;
  int d, s; float ea;
  if (e < E) { d = ei[E + e]; s = ei[e]; ea = eattr[e]; }
  else       { d = e - E;     s = e - E; ea = meanv[0]; }
  int pos = atomicAdd(&cursor[d], 1);
  epack[pos] = make_int2(s, __float_as_int(ea));
}

__global__ void weatt_kernel(const float* __restrict__ We, const float* __restrict__ atte,
                             float* __restrict__ weatt) {
  int t = threadIdx.x;
  float p = We[t] * atte[t];
#pragma unroll
  for (int off = 1; off < 64; off <<= 1) p += __shfl_xor(p, off, 64);
  if ((t & 63) == 0) weatt[t >> 6] = p;
}

// W [K][256] fp32  ->  Wt [256][K] bf16 (transposed + cast), coalesced reads
__global__ void wtrans_kernel(const float* __restrict__ W, unsigned short* __restrict__ Wt,
                              int K) {
  int t = blockIdx.x * blockDim.x + threadIdx.x;   // t over 256*K
  int n = t & 255, k = t >> 8;
  if (k >= K) return;
  Wt[(size_t)n * K + k] = f2bf(W[(size_t)k * 256 + n]);
}

// ---------------- MFMA bf16 GEMM + fused attention dots ----------------
// Y[M,256] = A[M,K] @ W[K,256].  Block: 256 thr = 4 waves, tile BM=32 x BN=256,
// BK=64. Wave w computes cols [w*64, w*64+64) == head w. Epilogue writes Hb
// (bf16) and asrc/adst (fp32 row-dots with att_s/att_d) via 16-lane reduce.
// A/B frag (16x16x32): row/col = lane%16, k = (lane/16)*8 + [0..8).
// C/D frag: col = lane&15, row = (lane>>4)*4 + reg.

template <int AF32>
__global__ __launch_bounds__(256) void gemm_att(const void* __restrict__ Ain,
                                                const unsigned short* __restrict__ Wt,
                                                unsigned short* __restrict__ Hb,
                                                const float* __restrict__ atts,
                                                const float* __restrict__ attd,
                                                float* __restrict__ asrc,
                                                float* __restrict__ adst,
                                                int M, int K) {
  __shared__ short As[32 * 64];    // [32][64] bf16, XOR-swizzled
  __shared__ short Bs[256 * 64];   // [256][64] bf16, XOR-swizzled
  const int tid = threadIdx.x;
  const int lane = tid & 63, wv = tid >> 6;
  const int l15 = lane & 15, l4 = lane >> 4;
  const int bm = blockIdx.x * 32;

  f32x4 acc[2][4] = {};

  for (int k0 = 0; k0 < K; k0 += 64) {
    // ---- stage A tile [32 rows][64 k] ----
    {
      int r = tid >> 3, kc = (tid & 7) * 8;
      int gr = bm + r;
      bf16x8 v = {};
      if (gr < M) {
        if (AF32) {
          const float* src = (const float*)Ain + (size_t)gr * K + k0 + kc;
          float4 f0 = *(const float4*)src;
          float4 f1 = *(const float4*)(src + 4);
          v[0] = (short)f2bf(f0.x); v[1] = (short)f2bf(f0.y);
          v[2] = (short)f2bf(f0.z); v[3] = (short)f2bf(f0.w);
          v[4] = (short)f2bf(f1.x); v[5] = (short)f2bf(f1.y);
          v[6] = (short)f2bf(f1.z); v[7] = (short)f2bf(f1.w);
        } else {
          v = *(const bf16x8*)((const unsigned short*)Ain + (size_t)gr * K + k0 + kc);
        }
      }
      *(bf16x8*)&As[(r * 64 + kc) ^ ((r & 7) << 3)] = v;
    }
    // ---- stage B tile [256 n][64 k] from Wt[n][K] ----
    {
      int c = tid & 7, nb = tid >> 3;
#pragma unroll
      for (int it = 0; it < 8; it++) {
        int n = nb + 32 * it;
        bf16x8 v = *(const bf16x8*)&Wt[(size_t)n * K + k0 + c * 8];
        *(bf16x8*)&Bs[(n * 64 + c * 8) ^ ((n & 7) << 3)] = v;
      }
    }
    __syncthreads();
    bf16x8 af[2][2], bfr[4][2];
#pragma unroll
    for (int rt = 0; rt < 2; rt++)
#pragma unroll
      for (int ks = 0; ks < 2; ks++) {
        int row = rt * 16 + l15;
        int kb = l4 * 8 + ks * 32;
        af[rt][ks] = *(const bf16x8*)&As[(row * 64 + kb) ^ ((row & 7) << 3)];
      }
#pragma unroll
    for (int ct = 0; ct < 4; ct++)
#pragma unroll
      for (int ks = 0; ks < 2; ks++) {
        int n = wv * 64 + ct * 16 + l15;
        int kb = l4 * 8 + ks * 32;
        bfr[ct][ks] = *(const bf16x8*)&Bs[(n * 64 + kb) ^ ((n & 7) << 3)];
      }
#pragma unroll
    for (int rt = 0; rt < 2; rt++)
#pragma unroll
      for (int ct = 0; ct < 4; ct++)
#pragma unroll
        for (int ks = 0; ks < 2; ks++)
          acc[rt][ct] = __builtin_amdgcn_mfma_f32_16x16x32_bf16(
              af[rt][ks], bfr[ct][ks], acc[rt][ct], 0, 0, 0);
    __syncthreads();
  }

  // ---- epilogue: Hb bf16 store + fused a_src/a_dst ----
  float s_att[4], d_att[4];
#pragma unroll
  for (int ct = 0; ct < 4; ct++) {
    s_att[ct] = atts[wv * 64 + ct * 16 + l15];
    d_att[ct] = attd[wv * 64 + ct * 16 + l15];
  }
  float ps[2][4] = {}, pd[2][4] = {};
#pragma unroll
  for (int rt = 0; rt < 2; rt++)
#pragma unroll
    for (int ct = 0; ct < 4; ct++)
#pragma unroll
      for (int i = 0; i < 4; i++) {
        float v = acc[rt][ct][i];
        int gr = bm + rt * 16 + l4 * 4 + i;
        if (gr < M) Hb[(size_t)gr * 256 + wv * 64 + ct * 16 + l15] = f2bf(v);
        ps[rt][i] = fmaf(v, s_att[ct], ps[rt][i]);
        pd[rt][i] = fmaf(v, d_att[ct], pd[rt][i]);
      }
#pragma unroll
  for (int rt = 0; rt < 2; rt++)
#pragma unroll
    for (int i = 0; i < 4; i++) {
#pragma unroll
      for (int off = 1; off < 16; off <<= 1) {
        ps[rt][i] += __shfl_xor(ps[rt][i], off, 64);
        pd[rt][i] += __shfl_xor(pd[rt][i], off, 64);
      }
    }
  if (l15 == 0) {
#pragma unroll
    for (int rt = 0; rt < 2; rt++)
#pragma unroll
      for (int i = 0; i < 4; i++) {
        int gr = bm + rt * 16 + l4 * 4 + i;
        if (gr < M) {
          asrc[gr * 4 + wv] = ps[rt][i];
          adst[gr * 4 + wv] = pd[rt][i];
        }
      }
  }
}

// ---------------- fused single-pass softmax + aggregation (bf16 gather) ----------------

template <int OUTBF>
__global__ __launch_bounds__(256) void gat_agg(const unsigned short* __restrict__ Hb,
                                               const float* __restrict__ asrc,
                                               const float* __restrict__ adst,
                                               const int* __restrict__ rowptr,
                                               const int2* __restrict__ epack,
                                               const float* __restrict__ weatt,
                                               const float* __restrict__ bias,
                                               unsigned short* __restrict__ outb,
                                               float* __restrict__ outf, int Nn) {
  int wid = (blockIdx.x * blockDim.x + threadIdx.x) >> 6;
  int lane = threadIdx.x & 63;
  if (wid >= Nn) return;
  int beg = rowptr[wid], end = rowptr[wid + 1];
  int hh = lane >> 4;
  float wa = weatt[hh];
  float ad = adst[wid * 4 + hh];
  unsigned co = (unsigned)lane * 4u;

  float m0 = -1e30f, s0 = 0.f, m1 = -1e30f, s1 = 0.f;
  float4 a0 = {0.f, 0.f, 0.f, 0.f}, a1 = {0.f, 0.f, 0.f, 0.f};
  int p = beg;
  for (; p + 1 < end; p += 2) {
    int2 e0 = epack[p], e1 = epack[p + 1];
    float al0 = fmaf(__int_as_float(e0.y), wa, asrc[e0.x * 4 + hh] + ad);
    float al1 = fmaf(__int_as_float(e1.y), wa, asrc[e1.x * 4 + hh] + ad);
    al0 = al0 > 0.f ? al0 : al0 * NEG_SLOPE;
    al1 = al1 > 0.f ? al1 : al1 * NEG_SLOPE;
    uint2 hv0 = *(const uint2*)&Hb[(size_t)((unsigned)e0.x * 256u + co)];
    uint2 hv1 = *(const uint2*)&Hb[(size_t)((unsigned)e1.x * 256u + co)];
    float mn0 = fmaxf(m0, al0);
    float c0 = __expf(m0 - mn0);
    float w0 = __expf(al0 - mn0);
    m0 = mn0;
    s0 = fmaf(s0, c0, w0);
    a0.x = fmaf(a0.x, c0, w0 * __uint_as_float(hv0.x << 16));
    a0.y = fmaf(a0.y, c0, w0 * __uint_as_float(hv0.x & 0xffff0000u));
    a0.z = fmaf(a0.z, c0, w0 * __uint_as_float(hv0.y << 16));
    a0.w = fmaf(a0.w, c0, w0 * __uint_as_float(hv0.y & 0xffff0000u));
    float mn1 = fmaxf(m1, al1);
    float c1 = __expf(m1 - mn1);
    float w1 = __expf(al1 - mn1);
    m1 = mn1;
    s1 = fmaf(s1, c1, w1);
    a1.x = fmaf(a1.x, c1, w1 * __uint_as_float(hv1.x << 16));
    a1.y = fmaf(a1.y, c1, w1 * __uint_as_float(hv1.x & 0xffff0000u));
    a1.z = fmaf(a1.z, c1, w1 * __uint_as_float(hv1.y << 16));
    a1.w = fmaf(a1.w, c1, w1 * __uint_as_float(hv1.y & 0xffff0000u));
  }
  if (p < end) {
    int2 e0 = epack[p];
    float al0 = fmaf(__int_as_float(e0.y), wa, asrc[e0.x * 4 + hh] + ad);
    al0 = al0 > 0.f ? al0 : al0 * NEG_SLOPE;
    uint2 hv0 = *(const uint2*)&Hb[(size_t)((unsigned)e0.x * 256u + co)];
    float mn0 = fmaxf(m0, al0);
    float c0 = __expf(m0 - mn0);
    float w0 = __expf(al0 - mn0);
    m0 = mn0;
    s0 = fmaf(s0, c0, w0);
    a0.x = fmaf(a0.x, c0, w0 * __uint_as_float(hv0.x << 16));
    a0.y = fmaf(a0.y, c0, w0 * __uint_as_float(hv0.x & 0xffff0000u));
    a0.z = fmaf(a0.z, c0, w0 * __uint_as_float(hv0.y << 16));
    a0.w = fmaf(a0.w, c0, w0 * __uint_as_float(hv0.y & 0xffff0000u));
  }
  float mm = fmaxf(m0, m1);
  float c0 = __expf(m0 - mm), c1 = __expf(m1 - mm);
  float ssum = fmaf(s0, c0, s1 * c1);
  float inv = 1.f / (ssum + 1e-16f);
  float4 b4 = *(const float4*)&bias[co];
  float4 r;
  r.x = fmaf(fmaf(a0.x, c0, a1.x * c1), inv, b4.x);
  r.y = fmaf(fmaf(a0.y, c0, a1.y * c1), inv, b4.y);
  r.z = fmaf(fmaf(a0.z, c0, a1.z * c1), inv, b4.z);
  r.w = fmaf(fmaf(a0.w, c0, a1.w * c1), inv, b4.w);
  if (OUTBF) {
    unsigned lo = (unsigned)f2bf(r.x) | ((unsigned)f2bf(r.y) << 16);
    unsigned hi = (unsigned)f2bf(r.z) | ((unsigned)f2bf(r.w) << 16);
    *(uint2*)&outb[(size_t)wid * 256 + co] = make_uint2(lo, hi);
  } else {
    *(float4*)&outf[(size_t)wid * 256 + co] = r;
  }
}

// ---------------- launcher ----------------

extern "C" void kernel_launch(void* const* d_in, const int* in_sizes, int n_in,
                              void* d_out, int out_size, void* d_ws, size_t ws_size,
                              hipStream_t stream) {
  (void)n_in; (void)out_size; (void)ws_size;
  const float* x     = (const float*)d_in[0];
  const int*   ei    = (const int*)d_in[1];
  const float* eattr = (const float*)d_in[3];
  const float* W1    = (const float*)d_in[4];
  const float* We1   = (const float*)d_in[5];
  const float* atts1 = (const float*)d_in[6];
  const float* attd1 = (const float*)d_in[7];
  const float* atte1 = (const float*)d_in[8];
  const float* b1    = (const float*)d_in[9];
  const float* W2    = (const float*)d_in[10];
  const float* We2   = (const float*)d_in[11];
  const float* atts2 = (const float*)d_in[12];
  const float* attd2 = (const float*)d_in[13];
  const float* atte2 = (const float*)d_in[14];
  const float* b2    = (const float*)d_in[15];
  float* out = (float*)d_out;

  const int Nn   = in_sizes[0] / 128;   // 50000
  const int E    = in_sizes[1] / 2;     // 800000
  const int Etot = E + Nn;              // 850000

  char* p = (char*)d_ws;
  auto alloc = [&](size_t bytes) { void* r = (void*)p; p += (bytes + 255) & ~(size_t)255; return r; };
  int*   rowptr  = (int*)alloc((size_t)(Nn + 1) * 4);
  int*   cursor  = (int*)alloc((size_t)Nn * 4);
  int*   counts  = (int*)alloc((size_t)Nn * 4);
  int2*  epack   = (int2*)alloc((size_t)Etot * 8);
  int*   bsum    = (int*)alloc(64 * 4);
  float* meanacc = (float*)alloc(4);
  float* meanv   = (float*)alloc(4);
  float* weatt1  = (float*)alloc(16);
  float* weatt2  = (float*)alloc(16);
  float* asrc    = (float*)alloc((size_t)Nn * 4 * 4);
  float* adst    = (float*)alloc((size_t)Nn * 4 * 4);
  unsigned short* hbuf = (unsigned short*)alloc((size_t)Nn * 256 * 2);  // GEMM out (bf16)
  unsigned short* h1b  = (unsigned short*)alloc((size_t)Nn * 256 * 2);  // layer-1 out (bf16)
  unsigned short* Wt1  = (unsigned short*)alloc((size_t)256 * 128 * 2);
  unsigned short* Wt2  = (unsigned short*)alloc((size_t)256 * 256 * 2);

  const int NB = (Nn + 4095) / 4096;

  hipMemsetAsync(counts, 0, (size_t)Nn * 4, stream);
  hipMemsetAsync(meanacc, 0, 4, stream);

  hist_kernel<<<(Etot + 255) / 256, 256, 0, stream>>>(ei, counts, E, Etot);
  mean_kernel<<<512, 256, 0, stream>>>(eattr, meanacc, E);
  scan_blocksum<<<NB, 256, 0, stream>>>(counts, bsum, Nn);
  scan_offsets<<<1, 64, 0, stream>>>(bsum, NB, rowptr + Nn, meanacc, meanv, E);
  scan_final<<<NB, 256, 0, stream>>>(counts, bsum, rowptr, Nn);
  hipMemcpyAsync(cursor, rowptr, (size_t)Nn * 4, hipMemcpyDeviceToDevice, stream);
  scatter_kernel<<<(Etot + 255) / 256, 256, 0, stream>>>(ei, eattr, meanv, cursor, epack, E, Etot);
  weatt_kernel<<<1, 256, 0, stream>>>(We1, atte1, weatt1);
  weatt_kernel<<<1, 256, 0, stream>>>(We2, atte2, weatt2);
  wtrans_kernel<<<128, 256, 0, stream>>>(W1, Wt1, 128);
  wtrans_kernel<<<256, 256, 0, stream>>>(W2, Wt2, 256);

  const int gemmBlocks = (Nn + 31) / 32;
  const int nodeBlocks = (Nn + 3) / 4;

  // ---- layer 1 ----
  gemm_att<1><<<gemmBlocks, 256, 0, stream>>>(x, Wt1, hbuf, atts1, attd1,
                                              asrc, adst, Nn, 128);
  gat_agg<1><<<nodeBlocks, 256, 0, stream>>>(hbuf, asrc, adst, rowptr, epack,
                                             weatt1, b1, h1b, nullptr, Nn);
  // ---- layer 2 ----
  gemm_att<0><<<gemmBlocks, 256, 0, stream>>>(h1b, Wt2, hbuf, atts2, attd2,
                                              asrc, adst, Nn, 256);
  gat_agg<0><<<nodeBlocks, 256, 0, stream>>>(hbuf, asrc, adst, rowptr, epack,
                                             weatt2, b2, nullptr, out, Nn);
}